// Round 7
// baseline (177.367 us; speedup 1.0000x reference)
//
#include <hip/hip_runtime.h>
#include <math.h>

#define T_SEQ   2048
#define EDIM    512
#define NHEADS  8
#define DHEAD   64
#define BATCH   4
#define WIN     128
#define TOPK    96

typedef _Float16 f16;
typedef f16 f16x2 __attribute__((ext_vector_type(2)));
typedef f16 f16x4 __attribute__((ext_vector_type(4)));
typedef f16 f16x8 __attribute__((ext_vector_type(8)));
typedef float f32x4 __attribute__((ext_vector_type(4)));

#define GLD_LDS(gp, lp) \
    __builtin_amdgcn_global_load_lds((const __attribute__((address_space(1))) void*)(gp), \
                                     (__attribute__((address_space(3))) void*)(lp), 16, 0, 0)

// ---------------------------------------------------------------------------
// fp32 -> f16 conversion of x, Wq, Wk, Wv, Wo. 4 elems/thread.
// ---------------------------------------------------------------------------
__global__ __launch_bounds__(256) void convert_all(
    const float* __restrict__ x,  const float* __restrict__ wq,
    const float* __restrict__ wk, const float* __restrict__ wv,
    const float* __restrict__ wo,
    f16* __restrict__ xh, f16* __restrict__ wqkvh, f16* __restrict__ woh)
{
    long i = ((long)blockIdx.x * 256 + threadIdx.x) * 4;
    const float* src; f16* dst; long off;
    if      (i < 4194304L) { src = x;  dst = xh;             off = i;            }
    else if (i < 4456448L) { src = wq; dst = wqkvh;          off = i - 4194304L; }
    else if (i < 4718592L) { src = wk; dst = wqkvh + 262144; off = i - 4456448L; }
    else if (i < 4980736L) { src = wv; dst = wqkvh + 524288; off = i - 4718592L; }
    else                   { src = wo; dst = woh;            off = i - 4980736L; }
    float4 v = *(const float4*)(src + off);
    f16x4 h; h.x = (f16)v.x; h.y = (f16)v.y; h.z = (f16)v.z; h.w = (f16)v.w;
    *(f16x4*)(dst + off) = h;
}

// ---------------------------------------------------------------------------
// QKV f16 MFMA GEMM: 128x128 tile, BK=64, 256 threads, 1D grid 768 with
// band-swizzle (8 m-blocks x 12 n-blocks per band, m-fastest) for L2 reuse.
// Epilogue: LDS-transpose, 16B coalesced stores.
//   Q,K -> f16 [B,H,T,64]; V -> f16 [B,H,64,T].
// ---------------------------------------------------------------------------
__global__ __launch_bounds__(256) void gemm_qkv(
    const f16* __restrict__ A, const f16* __restrict__ W,
    const float* __restrict__ b0, const float* __restrict__ b1,
    const float* __restrict__ b2,
    f16* __restrict__ cq, f16* __restrict__ ck, f16* __restrict__ cv)
{
    __shared__ f16 SH[16384];
    f16* Ash = SH;
    f16* Bsh = SH + 8192;

    const int bid  = blockIdx.x;            // 0..767
    const int band = bid / 96;              // 8 bands
    const int rem  = bid - band * 96;
    const int m0   = (band * 8 + (rem & 7)) * 128;
    const int n0   = (rem >> 3) * 128;

    const int tid  = threadIdx.x;
    const int w    = tid >> 6;
    const int lane = tid & 63;
    const int K    = 512;
    const int lr   = lane & 15;
    const int lk8  = (lane >> 4) * 8;

    f32x4 acc[4][4];
#pragma unroll
    for (int i = 0; i < 4; i++)
#pragma unroll
        for (int j = 0; j < 4; j++) acc[i][j] = (f32x4){0.f, 0.f, 0.f, 0.f};

    const int wmi = (w & 1) * 4;
    const int wni = (w >> 1) * 4;

    for (int k0 = 0; k0 < K; k0 += 64) {
#pragma unroll
        for (int cc = 0; cc < 4; cc++) {
            const int c  = w * 4 + cc;
            const int ms = c & 7, kp = c >> 3;
            const int kcol = k0 + kp * 32 + lk8;
            GLD_LDS(A + (size_t)(m0 + ms * 16 + lr) * K + kcol, Ash + c * 512);
            GLD_LDS(W + (size_t)(n0 + ms * 16 + lr) * K + kcol, Bsh + c * 512);
        }
        __syncthreads();

#pragma unroll
        for (int kp = 0; kp < 2; kp++) {
            f16x8 af[4], bf[4];
#pragma unroll
            for (int i = 0; i < 4; i++)
                af[i] = *(const f16x8*)(Ash + (kp * 8 + wmi + i) * 512 + lane * 8);
#pragma unroll
            for (int j = 0; j < 4; j++)
                bf[j] = *(const f16x8*)(Bsh + (kp * 8 + wni + j) * 512 + lane * 8);
#pragma unroll
            for (int i = 0; i < 4; i++)
#pragma unroll
                for (int j = 0; j < 4; j++)
                    acc[i][j] = __builtin_amdgcn_mfma_f32_16x16x32_f16(af[i], bf[j], acc[i][j], 0, 0, 0);
        }
        __syncthreads();
    }

    const int quad = lane >> 4;
    const int mat  = n0 >> 9;
    const float* bias = (mat == 0) ? b0 : ((mat == 1) ? b1 : b2);
    const int bb  = m0 >> 11;
    const int t0  = m0 & (T_SEQ - 1);
    const int hh0 = (n0 & 511) >> 6;

    if (mat < 2) {
#pragma unroll
        for (int i = 0; i < 4; i++) {
#pragma unroll
            for (int j = 0; j < 4; j++) {
                const int nl = (w >> 1) * 64 + j * 16 + lr;
                const float bvv = bias[(n0 & 511) + nl];
#pragma unroll
                for (int r = 0; r < 4; r++) {
                    const int ml = (w & 1) * 64 + i * 16 + quad * 4 + r;
                    SH[ml * 128 + (nl ^ (((ml >> 2) & 7) << 4))] = (f16)(acc[i][j][r] + bvv);
                }
            }
        }
        __syncthreads();
        f16* dst = (mat == 0) ? cq : ck;
#pragma unroll
        for (int s = 0; s < 8; s++) {
            const int c   = tid + 256 * s;
            const int row = c >> 4;
            const int nt  = (c & 15) * 8;
            const f16x8 vv = *(const f16x8*)&SH[row * 128 + (nt ^ (((row >> 2) & 7) << 4))];
            const int hh = hh0 + (nt >> 6);
            const int dd = nt & 63;
            *(f16x8*)(dst + ((size_t)((bb * NHEADS + hh) * T_SEQ) + t0 + row) * 64 + dd) = vv;
        }
    } else {
#pragma unroll
        for (int i = 0; i < 4; i++) {
#pragma unroll
            for (int j = 0; j < 4; j++) {
                const int nl = (w >> 1) * 64 + j * 16 + lr;
                const float bvv = bias[(n0 & 511) + nl];
                const int mlb = (w & 1) * 64 + i * 16 + quad * 4;
                f16x4 pk;
#pragma unroll
                for (int r = 0; r < 4; r++) pk[r] = (f16)(acc[i][j][r] + bvv);
                *(f16x4*)&SH[nl * 128 + ((mlb + 8 * (nl & 15)) & 127)] = pk;
            }
        }
        __syncthreads();
#pragma unroll
        for (int s = 0; s < 8; s++) {
            const int c    = tid + 256 * s;
            const int nrow = c >> 4;
            const int cht  = c & 15;
            const int chl  = (cht + (nrow & 15)) & 15;
            const f16x8 vv = *(const f16x8*)&SH[nrow * 128 + chl * 8];
            const int hh = hh0 + (nrow >> 6);
            const int dd = nrow & 63;
            *(f16x8*)(cv + ((size_t)((bb * NHEADS + hh) * 64 + dd)) * T_SEQ + t0 + cht * 8) = vv;
        }
    }
}

// ---------------------------------------------------------------------------
// Output-projection GEMM: 128x64 tile, BK=64, 1D grid 512 with band-swizzle.
// ---------------------------------------------------------------------------
__global__ __launch_bounds__(256) void gemm_o(
    const f16* __restrict__ A, const f16* __restrict__ W,
    const float* __restrict__ bias, float* __restrict__ C)
{
    __shared__ f16 Ash[16 * 512];
    __shared__ f16 Bsh[8 * 512];

    const int bid  = blockIdx.x;            // 0..511
    const int band = bid >> 6;              // 8 bands
    const int rem  = bid & 63;
    const int m0   = (band * 8 + (rem & 7)) * 128;
    const int n0   = (rem >> 3) * 64;

    const int tid  = threadIdx.x;
    const int w    = tid >> 6;
    const int lane = tid & 63;
    const int lr   = lane & 15;
    const int lk8  = (lane >> 4) * 8;

    f32x4 acc[4][2];
#pragma unroll
    for (int i = 0; i < 4; i++)
#pragma unroll
        for (int j = 0; j < 2; j++) acc[i][j] = (f32x4){0.f, 0.f, 0.f, 0.f};

    for (int k0 = 0; k0 < 512; k0 += 64) {
#pragma unroll
        for (int cc = 0; cc < 4; cc++) {
            const int c  = w * 4 + cc;
            const int ms = c & 7, kp = c >> 3;
            GLD_LDS(A + (size_t)(m0 + ms * 16 + lr) * 512 + k0 + kp * 32 + lk8, Ash + c * 512);
        }
#pragma unroll
        for (int cc = 0; cc < 2; cc++) {
            const int c  = w * 2 + cc;
            const int ns = c & 3, kp = c >> 2;
            GLD_LDS(W + (size_t)(n0 + ns * 16 + lr) * 512 + k0 + kp * 32 + lk8, Bsh + c * 512);
        }
        __syncthreads();

#pragma unroll
        for (int kp = 0; kp < 2; kp++) {
            f16x8 af[4], bf[2];
#pragma unroll
            for (int i = 0; i < 4; i++)
                af[i] = *(const f16x8*)(Ash + (kp * 8 + (w & 1) * 4 + i) * 512 + lane * 8);
#pragma unroll
            for (int j = 0; j < 2; j++)
                bf[j] = *(const f16x8*)(Bsh + (kp * 4 + (w >> 1) * 2 + j) * 512 + lane * 8);
#pragma unroll
            for (int i = 0; i < 4; i++)
#pragma unroll
                for (int j = 0; j < 2; j++)
                    acc[i][j] = __builtin_amdgcn_mfma_f32_16x16x32_f16(af[i], bf[j], acc[i][j], 0, 0, 0);
        }
        __syncthreads();
    }

    const int quad = lane >> 4;
#pragma unroll
    for (int i = 0; i < 4; i++) {
#pragma unroll
        for (int j = 0; j < 2; j++) {
            const int n  = n0 + (w >> 1) * 32 + j * 16 + lr;
            const float bv = bias[n];
#pragma unroll
            for (int r = 0; r < 4; r++) {
                const int m = m0 + (w & 1) * 64 + i * 16 + quad * 4 + r;
                C[(size_t)m * 512 + n] = acc[i][j][r] + bv;
            }
        }
    }
}

// ---------------------------------------------------------------------------
// Attention v6 = v4's EXACT fp32 top-96 (f16 selection failed: f16 score ties
// inflate the kept set -> 0.19 absmax) + v5's V register-prefetch.
// 512 threads (8 waves), (b,h) x 64 queries. LDS 79.6 KB -> 2 blocks/CU.
//   region A @0:     Qs[64][88] + Ks[192][88] f16 -> phase>=3: P[64][216] f16
//   region B @45056: Sc f32 [64][132] -> phase>=4: Vt[64][216] f16
//   ksqs @78848 f32[192]
// ---------------------------------------------------------------------------
__global__ __launch_bounds__(512, 4) void attn_v6(
    const f16* __restrict__ qh, const f16* __restrict__ kh,
    const f16* __restrict__ vtg, const float* __restrict__ logsig,
    f16* __restrict__ abh)
{
    __shared__ __align__(16) char smem[79616];
    f16*   Qs   = (f16*)smem;                 // [64][88]
    f16*   Ks   = (f16*)(smem + 11264);       // [192][88]
    f16*   P    = (f16*)smem;                 // [64][216] alias Qs/Ks
    float* Sc   = (float*)(smem + 45056);     // [64][132] f32
    f16*   Vt   = (f16*)(smem + 45056);       // [64][216] alias Sc
    float* ksqs = (float*)(smem + 78848);     // [192]

    const int tid = threadIdx.x, w = tid >> 6, lane = tid & 63;
    const int lr = lane & 15, quad = lane >> 4;
    const int q0 = blockIdx.x * 64, bh = blockIdx.y;
    const int h = bh & 7, b = bh >> 3;
    const size_t tb = (size_t)bh * T_SEQ;
    const int ks0 = q0 - 128;

    // ---- phase 0: V prefetch into registers (lands during phases 1-3) ----
    f16x8 vpre[3];
    int vd[3], vch[3];
#pragma unroll
    for (int s = 0; s < 3; s++) {
        const int i = tid + 512 * s;          // 0..1535
        vd[s] = i / 24; vch[s] = i % 24;
        const int t0 = ks0 + vch[s] * 8;
        f16x8 vv = {};
        if (t0 >= 0) vv = *(const f16x8*)(vtg + ((size_t)bh * 64 + vd[s]) * T_SEQ + t0);
        vpre[s] = vv;
    }

    // ---- phase 1: stage Q, K (+fused |k|^2) ----
    {
        const int row = tid >> 3, ch = tid & 7;
        f16x8 v = *(const f16x8*)(qh + (tb + q0 + row) * 64 + ch * 8);
        *(f16x8*)(Qs + row * 88 + ch * 8) = v;
    }
#pragma unroll
    for (int s = 0; s < 3; s++) {
        const int i = tid + 512 * s;
        const int row = i >> 3, ch = i & 7;
        const int kg = ks0 + row;
        f16x8 v = {};
        if (kg >= 0) v = *(const f16x8*)(kh + (tb + kg) * 64 + ch * 8);
        *(f16x8*)(Ks + row * 88 + ch * 8) = v;
        float ps = 0.f;
#pragma unroll
        for (int j = 0; j < 8; j++) { const float fv = (float)v[j]; ps += fv * fv; }
        ps += __shfl_xor(ps, 1);
        ps += __shfl_xor(ps, 2);
        ps += __shfl_xor(ps, 4);
        if (ch == 0) ksqs[row] = ps;
    }
    __syncthreads();

    // ---- phase 2: QK^T. wave = m-tile (w&3) x key-half (w>>2, 96 keys) ----
    const int mt  = w & 3;
    const int kh2 = w >> 2;
    f32x4 accQ[6];
#pragma unroll
    for (int jt = 0; jt < 6; jt++) accQ[jt] = (f32x4){0.f, 0.f, 0.f, 0.f};

#pragma unroll
    for (int kp = 0; kp < 2; kp++) {
        const f16x8 af = *(const f16x8*)(Qs + (mt * 16 + lr) * 88 + kp * 32 + quad * 8);
#pragma unroll
        for (int jt = 0; jt < 6; jt++) {
            const f16x8 bf = *(const f16x8*)(Ks + (kh2 * 96 + jt * 16 + lr) * 88 + kp * 32 + quad * 8);
            accQ[jt] = __builtin_amdgcn_mfma_f32_16x16x32_f16(af, bf, accQ[jt], 0, 0, 0);
        }
    }
    const float inv_s2 = __expf(-2.0f * logsig[h]);
#pragma unroll
    for (int jt = 0; jt < 6; jt++) {
        const int c  = kh2 * 96 + jt * 16 + lr;
        const float kq = ksqs[c];
        const int kg = ks0 + c;
#pragma unroll
        for (int r = 0; r < 4; r++) {
            const int dq = mt * 16 + quad * 4 + r;
            const unsigned wc = (unsigned)(c - dq - 1);
            if (wc < 128u) {
                Sc[dq * 132 + wc] = (kg >= 0) ? (accQ[jt][r] - 0.5f * kq) * inv_s2
                                              : -INFINITY;
            }
        }
    }
    __syncthreads();

    // ---- phase 3: EXACT top-96 via fp32 32-step ballot search, 4-query ILP ----
    const int wq8 = w * 8;
#pragma unroll 1
    for (int g = 0; g < 2; g++) {
        const int dq0 = wq8 + g * 4;
        float s0[4], s1[4], m[4];
        unsigned u0[4], u1[4], t[4];
#pragma unroll
        for (int qq = 0; qq < 4; qq++) {
            const int dq = dq0 + qq;
            s0[qq] = Sc[dq * 132 + lane];
            s1[qq] = Sc[dq * 132 + 64 + lane];
            const unsigned b0 = __float_as_uint(s0[qq]);
            const unsigned b1 = __float_as_uint(s1[qq]);
            u0[qq] = b0 ^ (unsigned)(((int)b0 >> 31) | 0x80000000);
            u1[qq] = b1 ^ (unsigned)(((int)b1 >> 31) | 0x80000000);
            // diagonal (wc=127, lane 63 of s1) is the row max: score is
            // monotone-decreasing in |q-k|^2.
            m[qq] = __uint_as_float(__builtin_amdgcn_readlane(__float_as_uint(s1[qq]), 63));
            t[qq] = 0u;
        }
#pragma unroll
        for (int bit = 31; bit >= 0; bit--) {
#pragma unroll
            for (int qq = 0; qq < 4; qq++) {
                const unsigned c = t[qq] | (1u << bit);
                const int n = __popcll(__ballot(u0[qq] >= c)) +
                              __popcll(__ballot(u1[qq] >= c));
                if (n >= TOPK) t[qq] = c;
            }
        }
#pragma unroll
        for (int qq = 0; qq < 4; qq++) {
            const int dq = dq0 + qq;
            const float p0 = (u0[qq] >= t[qq]) ? __expf(s0[qq] - m[qq]) : 0.f;
            const float p1 = (u1[qq] >= t[qq]) ? __expf(s1[qq] - m[qq]) : 0.f;
            P[dq * 216 + dq + 1 + lane]  = (f16)p0;
            P[dq * 216 + dq + 65 + lane] = (f16)p1;
            P[dq * 216 + ((lane <= dq) ? lane : lane + 128)] = (f16)0.f;
        }
    }
    __syncthreads();   // Sc dead; region B becomes Vt

    // ---- phase 4: write prefetched V to LDS ----
#pragma unroll
    for (int s = 0; s < 3; s++)
        *(f16x8*)(Vt + vd[s] * 216 + vch[s] * 8) = vpre[s];
    __syncthreads();

    // ---- phase 5: PV MFMA + ones-MFMA row sums ----
    const int nh = w >> 2;
    f32x4 accO[2];
#pragma unroll
    for (int nt = 0; nt < 2; nt++) accO[nt] = (f32x4){0.f, 0.f, 0.f, 0.f};
    f32x4 accS = (f32x4){0.f, 0.f, 0.f, 0.f};
    f16x8 onesf;
#pragma unroll
    for (int j = 0; j < 8; j++) onesf[j] = (f16)1.0f;

#pragma unroll
    for (int ks = 0; ks < 6; ks++) {
        const f16x8 pf = *(const f16x8*)(P + (mt * 16 + lr) * 216 + ks * 32 + quad * 8);
#pragma unroll
        for (int nt = 0; nt < 2; nt++) {
            const f16x8 vf = *(const f16x8*)(Vt + (nh * 32 + nt * 16 + lr) * 216 + ks * 32 + quad * 8);
            accO[nt] = __builtin_amdgcn_mfma_f32_16x16x32_f16(pf, vf, accO[nt], 0, 0, 0);
        }
        accS = __builtin_amdgcn_mfma_f32_16x16x32_f16(pf, onesf, accS, 0, 0, 0);
    }
    float inv[4];
#pragma unroll
    for (int r = 0; r < 4; r++) inv[r] = 1.0f / accS[r];

#pragma unroll
    for (int nt = 0; nt < 2; nt++) {
        const int d = nh * 32 + nt * 16 + lr;
#pragma unroll
        for (int r = 0; r < 4; r++) {
            const int q = q0 + mt * 16 + quad * 4 + r;
            abh[((size_t)(b * T_SEQ + q)) * 512 + h * 64 + d] = (f16)(accO[nt][r] * inv[r]);
        }
    }
}

// ---------------------------------------------------------------------------
extern "C" void kernel_launch(void* const* d_in, const int* in_sizes, int n_in,
                              void* d_out, int out_size, void* d_ws, size_t ws_size,
                              hipStream_t stream)
{
    const float* x      = (const float*)d_in[0];
    const float* Wq     = (const float*)d_in[1];
    const float* bq     = (const float*)d_in[2];
    const float* Wk     = (const float*)d_in[3];
    const float* bk     = (const float*)d_in[4];
    const float* Wv     = (const float*)d_in[5];
    const float* bv     = (const float*)d_in[6];
    const float* Wo     = (const float*)d_in[7];
    const float* bo     = (const float*)d_in[8];
    const float* logsig = (const float*)d_in[9];

    f16* xh    = (f16*)d_ws;              // 4,194,304
    f16* wqkvh = xh + 4194304;            // 786,432
    f16* woh   = wqkvh + 786432;          // 262,144
    f16* qh    = woh + 262144;            // 4,194,304  [B,H,T,64]
    f16* kh    = qh + 4194304;            // 4,194,304  [B,H,T,64]
    f16* vtg   = kh + 4194304;            // 4,194,304  [B,H,64,T]
    f16* abh   = xh;                      // alias: x dead after QKV GEMM

    convert_all<<<5120, 256, 0, stream>>>(x, Wq, Wk, Wv, Wo, xh, wqkvh, woh);

    gemm_qkv<<<768, 256, 0, stream>>>(xh, wqkvh, bq, bk, bv, qh, kh, vtg);

    attn_v6<<<dim3(T_SEQ / 64, BATCH * NHEADS), 512, 0, stream>>>(
        qh, kh, vtg, logsig, abh);

    gemm_o<<<512, 256, 0, stream>>>(abh, woh, bo, (float*)d_out);
}

// Round 8
// 174.737 us; speedup vs baseline: 1.0151x; 1.0151x over previous
//
#include <hip/hip_runtime.h>
#include <math.h>

#define T_SEQ   2048
#define EDIM    512
#define NHEADS  8
#define DHEAD   64
#define BATCH   4
#define WIN     128
#define TOPK    96

typedef _Float16 f16;
typedef f16 f16x2 __attribute__((ext_vector_type(2)));
typedef f16 f16x4 __attribute__((ext_vector_type(4)));
typedef f16 f16x8 __attribute__((ext_vector_type(8)));
typedef float f32x4 __attribute__((ext_vector_type(4)));

#define GLD_LDS(gp, lp) \
    __builtin_amdgcn_global_load_lds((const __attribute__((address_space(1))) void*)(gp), \
                                     (__attribute__((address_space(3))) void*)(lp), 16, 0, 0)

// ---------------------------------------------------------------------------
// fp32 -> f16 conversion of x, Wq, Wk, Wv, Wo. 4 elems/thread.
// ---------------------------------------------------------------------------
__global__ __launch_bounds__(256) void convert_all(
    const float* __restrict__ x,  const float* __restrict__ wq,
    const float* __restrict__ wk, const float* __restrict__ wv,
    const float* __restrict__ wo,
    f16* __restrict__ xh, f16* __restrict__ wqkvh, f16* __restrict__ woh)
{
    long i = ((long)blockIdx.x * 256 + threadIdx.x) * 4;
    const float* src; f16* dst; long off;
    if      (i < 4194304L) { src = x;  dst = xh;             off = i;            }
    else if (i < 4456448L) { src = wq; dst = wqkvh;          off = i - 4194304L; }
    else if (i < 4718592L) { src = wk; dst = wqkvh + 262144; off = i - 4456448L; }
    else if (i < 4980736L) { src = wv; dst = wqkvh + 524288; off = i - 4718592L; }
    else                   { src = wo; dst = woh;            off = i - 4980736L; }
    float4 v = *(const float4*)(src + off);
    f16x4 h; h.x = (f16)v.x; h.y = (f16)v.y; h.z = (f16)v.z; h.w = (f16)v.w;
    *(f16x4*)(dst + off) = h;
}

// ---------------------------------------------------------------------------
// QKV f16 MFMA GEMM: 128x128 tile, BK=64, 256 threads, 2D grid dim3(64,12)
// (m fastest: 64 consecutive blocks share one W-tile; A-tile reuse stride 64
// stays XCD-resident — measured better than 1D band-swizzle).
// Epilogue: LDS-transpose, 16B coalesced stores.
//   Q,K -> f16 [B,H,T,64]; V -> f16 [B,H,64,T].
// ---------------------------------------------------------------------------
__global__ __launch_bounds__(256) void gemm_qkv(
    const f16* __restrict__ A, const f16* __restrict__ W,
    const float* __restrict__ b0, const float* __restrict__ b1,
    const float* __restrict__ b2,
    f16* __restrict__ cq, f16* __restrict__ ck, f16* __restrict__ cv)
{
    __shared__ f16 SH[16384];
    f16* Ash = SH;
    f16* Bsh = SH + 8192;

    const int m0   = blockIdx.x * 128;
    const int n0   = blockIdx.y * 128;

    const int tid  = threadIdx.x;
    const int w    = tid >> 6;
    const int lane = tid & 63;
    const int K    = 512;
    const int lr   = lane & 15;
    const int lk8  = (lane >> 4) * 8;

    f32x4 acc[4][4];
#pragma unroll
    for (int i = 0; i < 4; i++)
#pragma unroll
        for (int j = 0; j < 4; j++) acc[i][j] = (f32x4){0.f, 0.f, 0.f, 0.f};

    const int wmi = (w & 1) * 4;
    const int wni = (w >> 1) * 4;

    for (int k0 = 0; k0 < K; k0 += 64) {
#pragma unroll
        for (int cc = 0; cc < 4; cc++) {
            const int c  = w * 4 + cc;
            const int ms = c & 7, kp = c >> 3;
            const int kcol = k0 + kp * 32 + lk8;
            GLD_LDS(A + (size_t)(m0 + ms * 16 + lr) * K + kcol, Ash + c * 512);
            GLD_LDS(W + (size_t)(n0 + ms * 16 + lr) * K + kcol, Bsh + c * 512);
        }
        __syncthreads();

#pragma unroll
        for (int kp = 0; kp < 2; kp++) {
            f16x8 af[4], bf[4];
#pragma unroll
            for (int i = 0; i < 4; i++)
                af[i] = *(const f16x8*)(Ash + (kp * 8 + wmi + i) * 512 + lane * 8);
#pragma unroll
            for (int j = 0; j < 4; j++)
                bf[j] = *(const f16x8*)(Bsh + (kp * 8 + wni + j) * 512 + lane * 8);
#pragma unroll
            for (int i = 0; i < 4; i++)
#pragma unroll
                for (int j = 0; j < 4; j++)
                    acc[i][j] = __builtin_amdgcn_mfma_f32_16x16x32_f16(af[i], bf[j], acc[i][j], 0, 0, 0);
        }
        __syncthreads();
    }

    const int quad = lane >> 4;
    const int mat  = n0 >> 9;
    const float* bias = (mat == 0) ? b0 : ((mat == 1) ? b1 : b2);
    const int bb  = m0 >> 11;
    const int t0  = m0 & (T_SEQ - 1);
    const int hh0 = (n0 & 511) >> 6;

    if (mat < 2) {
#pragma unroll
        for (int i = 0; i < 4; i++) {
#pragma unroll
            for (int j = 0; j < 4; j++) {
                const int nl = (w >> 1) * 64 + j * 16 + lr;
                const float bvv = bias[(n0 & 511) + nl];
#pragma unroll
                for (int r = 0; r < 4; r++) {
                    const int ml = (w & 1) * 64 + i * 16 + quad * 4 + r;
                    SH[ml * 128 + (nl ^ (((ml >> 2) & 7) << 4))] = (f16)(acc[i][j][r] + bvv);
                }
            }
        }
        __syncthreads();
        f16* dst = (mat == 0) ? cq : ck;
#pragma unroll
        for (int s = 0; s < 8; s++) {
            const int c   = tid + 256 * s;
            const int row = c >> 4;
            const int nt  = (c & 15) * 8;
            const f16x8 vv = *(const f16x8*)&SH[row * 128 + (nt ^ (((row >> 2) & 7) << 4))];
            const int hh = hh0 + (nt >> 6);
            const int dd = nt & 63;
            *(f16x8*)(dst + ((size_t)((bb * NHEADS + hh) * T_SEQ) + t0 + row) * 64 + dd) = vv;
        }
    } else {
#pragma unroll
        for (int i = 0; i < 4; i++) {
#pragma unroll
            for (int j = 0; j < 4; j++) {
                const int nl = (w >> 1) * 64 + j * 16 + lr;
                const float bvv = bias[(n0 & 511) + nl];
                const int mlb = (w & 1) * 64 + i * 16 + quad * 4;
                f16x4 pk;
#pragma unroll
                for (int r = 0; r < 4; r++) pk[r] = (f16)(acc[i][j][r] + bvv);
                *(f16x4*)&SH[nl * 128 + ((mlb + 8 * (nl & 15)) & 127)] = pk;
            }
        }
        __syncthreads();
#pragma unroll
        for (int s = 0; s < 8; s++) {
            const int c    = tid + 256 * s;
            const int nrow = c >> 4;
            const int cht  = c & 15;
            const int chl  = (cht + (nrow & 15)) & 15;
            const f16x8 vv = *(const f16x8*)&SH[nrow * 128 + chl * 8];
            const int hh = hh0 + (nrow >> 6);
            const int dd = nrow & 63;
            *(f16x8*)(cv + ((size_t)((bb * NHEADS + hh) * 64 + dd)) * T_SEQ + t0 + cht * 8) = vv;
        }
    }
}

// ---------------------------------------------------------------------------
// Output-projection GEMM: 128x64 tile, BK=64, 2D grid dim3(64,8).
// ---------------------------------------------------------------------------
__global__ __launch_bounds__(256) void gemm_o(
    const f16* __restrict__ A, const f16* __restrict__ W,
    const float* __restrict__ bias, float* __restrict__ C)
{
    __shared__ f16 Ash[16 * 512];
    __shared__ f16 Bsh[8 * 512];

    const int m0   = blockIdx.x * 128;
    const int n0   = blockIdx.y * 64;

    const int tid  = threadIdx.x;
    const int w    = tid >> 6;
    const int lane = tid & 63;
    const int lr   = lane & 15;
    const int lk8  = (lane >> 4) * 8;

    f32x4 acc[4][2];
#pragma unroll
    for (int i = 0; i < 4; i++)
#pragma unroll
        for (int j = 0; j < 2; j++) acc[i][j] = (f32x4){0.f, 0.f, 0.f, 0.f};

    for (int k0 = 0; k0 < 512; k0 += 64) {
#pragma unroll
        for (int cc = 0; cc < 4; cc++) {
            const int c  = w * 4 + cc;
            const int ms = c & 7, kp = c >> 3;
            GLD_LDS(A + (size_t)(m0 + ms * 16 + lr) * 512 + k0 + kp * 32 + lk8, Ash + c * 512);
        }
#pragma unroll
        for (int cc = 0; cc < 2; cc++) {
            const int c  = w * 2 + cc;
            const int ns = c & 3, kp = c >> 2;
            GLD_LDS(W + (size_t)(n0 + ns * 16 + lr) * 512 + k0 + kp * 32 + lk8, Bsh + c * 512);
        }
        __syncthreads();

#pragma unroll
        for (int kp = 0; kp < 2; kp++) {
            f16x8 af[4], bf[2];
#pragma unroll
            for (int i = 0; i < 4; i++)
                af[i] = *(const f16x8*)(Ash + (kp * 8 + (w & 1) * 4 + i) * 512 + lane * 8);
#pragma unroll
            for (int j = 0; j < 2; j++)
                bf[j] = *(const f16x8*)(Bsh + (kp * 4 + (w >> 1) * 2 + j) * 512 + lane * 8);
#pragma unroll
            for (int i = 0; i < 4; i++)
#pragma unroll
                for (int j = 0; j < 2; j++)
                    acc[i][j] = __builtin_amdgcn_mfma_f32_16x16x32_f16(af[i], bf[j], acc[i][j], 0, 0, 0);
        }
        __syncthreads();
    }

    const int quad = lane >> 4;
#pragma unroll
    for (int i = 0; i < 4; i++) {
#pragma unroll
        for (int j = 0; j < 2; j++) {
            const int n  = n0 + (w >> 1) * 32 + j * 16 + lr;
            const float bv = bias[n];
#pragma unroll
            for (int r = 0; r < 4; r++) {
                const int m = m0 + (w & 1) * 64 + i * 16 + quad * 4 + r;
                C[(size_t)m * 512 + n] = acc[i][j][r] + bv;
            }
        }
    }
}

// ---------------------------------------------------------------------------
// Attention v6: exact fp32 top-96 (32-step ballot binary search) + V register
// prefetch. 512 threads (8 waves), (b,h) x 64 queries. LDS 79.6 KB.
//   region A @0:     Qs[64][88] + Ks[192][88] f16 -> phase>=3: P[64][216] f16
//   region B @45056: Sc f32 [64][132] -> phase>=4: Vt[64][216] f16
//   ksqs @78848 f32[192]
// ---------------------------------------------------------------------------
__global__ __launch_bounds__(512, 4) void attn_v6(
    const f16* __restrict__ qh, const f16* __restrict__ kh,
    const f16* __restrict__ vtg, const float* __restrict__ logsig,
    f16* __restrict__ abh)
{
    __shared__ __align__(16) char smem[79616];
    f16*   Qs   = (f16*)smem;                 // [64][88]
    f16*   Ks   = (f16*)(smem + 11264);       // [192][88]
    f16*   P    = (f16*)smem;                 // [64][216] alias Qs/Ks
    float* Sc   = (float*)(smem + 45056);     // [64][132] f32
    f16*   Vt   = (f16*)(smem + 45056);       // [64][216] alias Sc
    float* ksqs = (float*)(smem + 78848);     // [192]

    const int tid = threadIdx.x, w = tid >> 6, lane = tid & 63;
    const int lr = lane & 15, quad = lane >> 4;
    const int q0 = blockIdx.x * 64, bh = blockIdx.y;
    const int h = bh & 7, b = bh >> 3;
    const size_t tb = (size_t)bh * T_SEQ;
    const int ks0 = q0 - 128;

    // ---- phase 0: V prefetch into registers (lands during phases 1-3) ----
    f16x8 vpre[3];
    int vd[3], vch[3];
#pragma unroll
    for (int s = 0; s < 3; s++) {
        const int i = tid + 512 * s;          // 0..1535
        vd[s] = i / 24; vch[s] = i % 24;
        const int t0 = ks0 + vch[s] * 8;
        f16x8 vv = {};
        if (t0 >= 0) vv = *(const f16x8*)(vtg + ((size_t)bh * 64 + vd[s]) * T_SEQ + t0);
        vpre[s] = vv;
    }

    // ---- phase 1: stage Q, K (+fused |k|^2) ----
    {
        const int row = tid >> 3, ch = tid & 7;
        f16x8 v = *(const f16x8*)(qh + (tb + q0 + row) * 64 + ch * 8);
        *(f16x8*)(Qs + row * 88 + ch * 8) = v;
    }
#pragma unroll
    for (int s = 0; s < 3; s++) {
        const int i = tid + 512 * s;
        const int row = i >> 3, ch = i & 7;
        const int kg = ks0 + row;
        f16x8 v = {};
        if (kg >= 0) v = *(const f16x8*)(kh + (tb + kg) * 64 + ch * 8);
        *(f16x8*)(Ks + row * 88 + ch * 8) = v;
        float ps = 0.f;
#pragma unroll
        for (int j = 0; j < 8; j++) { const float fv = (float)v[j]; ps += fv * fv; }
        ps += __shfl_xor(ps, 1);
        ps += __shfl_xor(ps, 2);
        ps += __shfl_xor(ps, 4);
        if (ch == 0) ksqs[row] = ps;
    }
    __syncthreads();

    // ---- phase 2: QK^T. wave = m-tile (w&3) x key-half (w>>2, 96 keys) ----
    const int mt  = w & 3;
    const int kh2 = w >> 2;
    f32x4 accQ[6];
#pragma unroll
    for (int jt = 0; jt < 6; jt++) accQ[jt] = (f32x4){0.f, 0.f, 0.f, 0.f};

#pragma unroll
    for (int kp = 0; kp < 2; kp++) {
        const f16x8 af = *(const f16x8*)(Qs + (mt * 16 + lr) * 88 + kp * 32 + quad * 8);
#pragma unroll
        for (int jt = 0; jt < 6; jt++) {
            const f16x8 bf = *(const f16x8*)(Ks + (kh2 * 96 + jt * 16 + lr) * 88 + kp * 32 + quad * 8);
            accQ[jt] = __builtin_amdgcn_mfma_f32_16x16x32_f16(af, bf, accQ[jt], 0, 0, 0);
        }
    }
    const float inv_s2 = __expf(-2.0f * logsig[h]);
#pragma unroll
    for (int jt = 0; jt < 6; jt++) {
        const int c  = kh2 * 96 + jt * 16 + lr;
        const float kq = ksqs[c];
        const int kg = ks0 + c;
#pragma unroll
        for (int r = 0; r < 4; r++) {
            const int dq = mt * 16 + quad * 4 + r;
            const unsigned wc = (unsigned)(c - dq - 1);
            if (wc < 128u) {
                Sc[dq * 132 + wc] = (kg >= 0) ? (accQ[jt][r] - 0.5f * kq) * inv_s2
                                              : -INFINITY;
            }
        }
    }
    __syncthreads();

    // ---- phase 3: EXACT top-96 via fp32 32-step ballot search, 4-query ILP ----
    const int wq8 = w * 8;
#pragma unroll 1
    for (int g = 0; g < 2; g++) {
        const int dq0 = wq8 + g * 4;
        float s0[4], s1[4], m[4];
        unsigned u0[4], u1[4], t[4];
#pragma unroll
        for (int qq = 0; qq < 4; qq++) {
            const int dq = dq0 + qq;
            s0[qq] = Sc[dq * 132 + lane];
            s1[qq] = Sc[dq * 132 + 64 + lane];
            const unsigned b0 = __float_as_uint(s0[qq]);
            const unsigned b1 = __float_as_uint(s1[qq]);
            u0[qq] = b0 ^ (unsigned)(((int)b0 >> 31) | 0x80000000);
            u1[qq] = b1 ^ (unsigned)(((int)b1 >> 31) | 0x80000000);
            // diagonal (wc=127, lane 63 of s1) is the row max: score is
            // monotone-decreasing in |q-k|^2.
            m[qq] = __uint_as_float(__builtin_amdgcn_readlane(__float_as_uint(s1[qq]), 63));
            t[qq] = 0u;
        }
#pragma unroll
        for (int bit = 31; bit >= 0; bit--) {
#pragma unroll
            for (int qq = 0; qq < 4; qq++) {
                const unsigned c = t[qq] | (1u << bit);
                const int n = __popcll(__ballot(u0[qq] >= c)) +
                              __popcll(__ballot(u1[qq] >= c));
                if (n >= TOPK) t[qq] = c;
            }
        }
#pragma unroll
        for (int qq = 0; qq < 4; qq++) {
            const int dq = dq0 + qq;
            const float p0 = (u0[qq] >= t[qq]) ? __expf(s0[qq] - m[qq]) : 0.f;
            const float p1 = (u1[qq] >= t[qq]) ? __expf(s1[qq] - m[qq]) : 0.f;
            P[dq * 216 + dq + 1 + lane]  = (f16)p0;
            P[dq * 216 + dq + 65 + lane] = (f16)p1;
            P[dq * 216 + ((lane <= dq) ? lane : lane + 128)] = (f16)0.f;
        }
    }
    __syncthreads();   // Sc dead; region B becomes Vt

    // ---- phase 4: write prefetched V to LDS ----
#pragma unroll
    for (int s = 0; s < 3; s++)
        *(f16x8*)(Vt + vd[s] * 216 + vch[s] * 8) = vpre[s];
    __syncthreads();

    // ---- phase 5: PV MFMA + ones-MFMA row sums ----
    const int nh = w >> 2;
    f32x4 accO[2];
#pragma unroll
    for (int nt = 0; nt < 2; nt++) accO[nt] = (f32x4){0.f, 0.f, 0.f, 0.f};
    f32x4 accS = (f32x4){0.f, 0.f, 0.f, 0.f};
    f16x8 onesf;
#pragma unroll
    for (int j = 0; j < 8; j++) onesf[j] = (f16)1.0f;

#pragma unroll
    for (int ks = 0; ks < 6; ks++) {
        const f16x8 pf = *(const f16x8*)(P + (mt * 16 + lr) * 216 + ks * 32 + quad * 8);
#pragma unroll
        for (int nt = 0; nt < 2; nt++) {
            const f16x8 vf = *(const f16x8*)(Vt + (nh * 32 + nt * 16 + lr) * 216 + ks * 32 + quad * 8);
            accO[nt] = __builtin_amdgcn_mfma_f32_16x16x32_f16(pf, vf, accO[nt], 0, 0, 0);
        }
        accS = __builtin_amdgcn_mfma_f32_16x16x32_f16(pf, onesf, accS, 0, 0, 0);
    }
    float inv[4];
#pragma unroll
    for (int r = 0; r < 4; r++) inv[r] = 1.0f / accS[r];

#pragma unroll
    for (int nt = 0; nt < 2; nt++) {
        const int d = nh * 32 + nt * 16 + lr;
#pragma unroll
        for (int r = 0; r < 4; r++) {
            const int q = q0 + mt * 16 + quad * 4 + r;
            abh[((size_t)(b * T_SEQ + q)) * 512 + h * 64 + d] = (f16)(accO[nt][r] * inv[r]);
        }
    }
}

// ---------------------------------------------------------------------------
extern "C" void kernel_launch(void* const* d_in, const int* in_sizes, int n_in,
                              void* d_out, int out_size, void* d_ws, size_t ws_size,
                              hipStream_t stream)
{
    const float* x      = (const float*)d_in[0];
    const float* Wq     = (const float*)d_in[1];
    const float* bq     = (const float*)d_in[2];
    const float* Wk     = (const float*)d_in[3];
    const float* bk     = (const float*)d_in[4];
    const float* Wv     = (const float*)d_in[5];
    const float* bv     = (const float*)d_in[6];
    const float* Wo     = (const float*)d_in[7];
    const float* bo     = (const float*)d_in[8];
    const float* logsig = (const float*)d_in[9];

    f16* xh    = (f16*)d_ws;              // 4,194,304
    f16* wqkvh = xh + 4194304;            // 786,432
    f16* woh   = wqkvh + 786432;          // 262,144
    f16* qh    = woh + 262144;            // 4,194,304  [B,H,T,64]
    f16* kh    = qh + 4194304;            // 4,194,304  [B,H,T,64]
    f16* vtg   = kh + 4194304;            // 4,194,304  [B,H,64,T]
    f16* abh   = xh;                      // alias: x dead after QKV GEMM

    convert_all<<<5120, 256, 0, stream>>>(x, Wq, Wk, Wv, Wo, xh, wqkvh, woh);

    gemm_qkv<<<dim3(64, 12), 256, 0, stream>>>(xh, wqkvh, bq, bk, bv, qh, kh, vtg);

    attn_v6<<<dim3(T_SEQ / 64, BATCH * NHEADS), 512, 0, stream>>>(
        qh, kh, vtg, logsig, abh);

    gemm_o<<<dim3(64, 8), 256, 0, stream>>>(abh, woh, bo, (float*)d_out);
}